// Round 7
// baseline (148.559 us; speedup 1.0000x reference)
//
#include <hip/hip_runtime.h>

#define N0 4096
#define N1 2048
#define N2 1024

// lane i gets lane i-1's value (within 16-lane DPP row); row-lane 0 -> 0 (overridden)
__device__ __forceinline__ float dpp_from_left(float x) {
    return __int_as_float(__builtin_amdgcn_update_dpp(0, __float_as_int(x), 0x111, 0xf, 0xf, false));
}
// lane i gets lane i+1's value; row-lane 15 -> 0 (overridden)
__device__ __forceinline__ float dpp_from_right(float x) {
    return __int_as_float(__builtin_amdgcn_update_dpp(0, __float_as_int(x), 0x101, 0xf, 0xf, false));
}

// ============ restrict: fc = restrict(f + 0.2*L(f)) — zero LDS (R5, verified) ============
__global__ __launch_bounds__(256, 4) void k_res_restrict(const float* __restrict__ f,
                                                         float* __restrict__ fc,
                                                         int n, int nc) {
    const int tid = threadIdx.x;
    const int tx = tid & 15, ty = tid >> 4;
    const int fy0 = blockIdx.y * 64, fx0 = blockIdx.x * 64;
    const bool edge = (blockIdx.x == 0) | (blockIdx.y == 0) |
                      (blockIdx.x == gridDim.x - 1) | (blockIdx.y == gridDim.y - 1);

    float fa[6][6];
    #pragma unroll
    for (int rr = 0; rr < 6; ++rr) {
        int gy = fy0 + 4 * ty - 1 + rr;
        gy = max(0, min(n - 1, gy));
        const float* rowp = f + (size_t)gy * n;
        float4 o = *(const float4*)(rowp + fx0 + 4 * tx);
        fa[rr][1] = o.x; fa[rr][2] = o.y; fa[rr][3] = o.z; fa[rr][4] = o.w;
        fa[rr][0] = dpp_from_left(o.w);
        fa[rr][5] = dpp_from_right(o.x);
        if (tx == 0)  fa[rr][0] = rowp[max(0, fx0 - 1)];
        if (tx == 15) fa[rr][5] = rowp[min(n - 1, fx0 + 64)];
    }

    float rv[4][4];
    #pragma unroll
    for (int i = 0; i < 4; ++i) {
        #pragma unroll
        for (int j = 0; j < 4; ++j) {
            float c = fa[1 + i][1 + j];
            rv[i][j] = c + 0.2f * (fa[i][1 + j] + fa[2 + i][1 + j] +
                                   fa[1 + i][j] + fa[1 + i][2 + j] - 4.0f * c);
        }
    }
    if (edge) {
        #pragma unroll
        for (int i = 0; i < 4; ++i)
            #pragma unroll
            for (int j = 0; j < 4; ++j) {
                int gy = fy0 + 4 * ty + i, gx = fx0 + 4 * tx + j;
                if (gy == 0 || gy == n - 1 || gx == 0 || gx == n - 1)
                    rv[i][j] = fa[1 + i][1 + j];
            }
    }
    #pragma unroll
    for (int da = 0; da < 2; ++da) {
        float2 o;
        o.x = 0.25f * (rv[2*da][0] + rv[2*da][1] + rv[2*da+1][0] + rv[2*da+1][1]);
        o.y = 0.25f * (rv[2*da][2] + rv[2*da][3] + rv[2*da+1][2] + rv[2*da+1][3]);
        *(float2*)(fc + (size_t)(fy0 / 2 + 2 * ty + da) * nc + (fx0 / 2 + 2 * tx)) = o;
    }
}

// ====== strip smooth: u = jacobi(cf*f + cs*prolong(uc), f), optional fused residual ======
// Each wave owns a 256-col x 16-row strip; rolling registers over rows; zero LDS/barriers.
template <bool RESID>
__global__ __launch_bounds__(256, 4) void k_smooth_strip(
        const float* __restrict__ f, const float* __restrict__ uc,
        float* __restrict__ u, int n, int m, float cf, float cs,
        double* __restrict__ pT, double* __restrict__ pF, int nChunks) {
    const int tid  = threadIdx.x;
    const int lane = tid & 63;
    const int w    = tid >> 6;
    const int chunk = blockIdx.x;
    const int strip = blockIdx.y * 4 + w;
    const int y0 = strip * 16;
    const int c0 = chunk * 256 + 4 * lane;      // own fine col base (4 cols)
    const int C  = chunk * 128 + 2 * lane;      // own coarse col base (2 cols)
    const bool laneL = (lane == 0), laneR = (lane == 63);
    const bool sideLane = laneL || laneR;
    const bool gL = (chunk == 0) && laneL;              // global col 0 in this lane's tile
    const bool gR = (chunk == nChunks - 1) && laneR;    // global col n-1
    const int fsCol = laneL ? max(0, c0 - 2) : min(n - 2, c0 + 4);
    const int ucSideCol = laneL ? max(0, C - 2) : min(m - 2, C + 2);
    const float n2 = (float)n * (float)n;

    // ---- rolling state ----
    float f0_[4], f1_[4], f2_[4];
    float v0_[4], v1_[4], v2_[4];
    float u0_[4], u1_[4], u2_[4];
    float4 fN; float2 fsN = make_float2(0.f, 0.f);
    float fsA = 0.f, fsB = 0.f, fsAprev = 0.f;
    float vsA_c = 0.f, vsA_m1 = 0.f, vsA_m2 = 0.f, vsB_c = 0.f, vsB_m1 = 0.f;
    float usA_c = 0.f, usA_p = 0.f;
    float hLo0, hLo1, hLo2, hLo3, hLoA, hLoB;
    float hHi0, hHi1, hHi2, hHi3, hHiA, hHiB;
    float2 ucN, ucNs = make_float2(0.f, 0.f);
    float accT = 0.f, accF = 0.f;
    #pragma unroll
    for (int j = 0; j < 4; ++j) { f0_[j]=f1_[j]=f2_[j]=0.f; v0_[j]=v1_[j]=v2_[j]=0.f; u0_[j]=u1_[j]=u2_[j]=0.f; }

    auto loadUC = [&](int ar, float2& o, float2& os) {
        const float* cp = uc + (size_t)max(0, min(m - 1, ar)) * m;
        o = *(const float2*)(cp + C);
        if (sideLane) os = *(const float2*)(cp + ucSideCol);
    };
    auto computeH = [&](float2 o, float2 os,
                        float& o0, float& o1, float& o2, float& o3, float& oA, float& oB) {
        float a0v = cs * o.x, a1v = cs * o.y;
        float sx = cs * os.x, sy = cs * os.y;
        float uL = __shfl_up(a1v, 1);
        float uR = __shfl_down(a0v, 1);
        if (laneL) uL = sy;     // cs*uc[C-1]
        if (laneR) uR = sx;     // cs*uc[C+2]
        o0 = 0.5f * uL  + 1.5f * a0v;
        o1 = 1.5f * a0v + 0.5f * a1v;
        o2 = 0.5f * a0v + 1.5f * a1v;
        o3 = 1.5f * a1v + 0.5f * uR;
        oA = laneL ? (1.5f * sy + 0.5f * a0v) : (1.5f * a1v + 0.5f * sx);   // col c0-1 | c0+4
        oB = laneL ? (0.5f * sx + 1.5f * sy) : (1.5f * sx + 0.5f * sy);     // col c0-2 | c0+5
    };

    // ---- prolog: coarse rows a0-2 (Lo), a0-1 (Hi), prefetch a0; f row y0-2 ----
    const int a0 = y0 >> 1;
    {
        float2 t0, t1s = make_float2(0.f, 0.f);
        loadUC(a0 - 2, t0, t1s);
        computeH(t0, t1s, hLo0, hLo1, hLo2, hLo3, hLoA, hLoB);
        loadUC(a0 - 1, t0, t1s);
        computeH(t0, t1s, hHi0, hHi1, hHi2, hHi3, hHiA, hHiB);
        loadUC(a0, ucN, ucNs);
        int fy = max(0, y0 - 2);
        const float* rp = f + (size_t)fy * n;
        fN = *(const float4*)(rp + c0);
        if (sideLane) fsN = *(const float2*)(rp + fsCol);
    }

    #pragma unroll
    for (int i = 0; i < 20; ++i) {
        const int yl = y0 - 2 + i;
        // ---- consume prefetched f row yl; issue row yl+1 ----
        float4 fNew = fN;
        float2 fsNew = fsN;
        {
            int fy = min(n - 1, max(0, yl + 1));
            const float* rp = f + (size_t)fy * n;
            fN = *(const float4*)(rp + c0);
            if (sideLane) fsN = *(const float2*)(rp + fsCol);
        }
        #pragma unroll
        for (int j = 0; j < 4; ++j) { f0_[j] = f1_[j]; f1_[j] = f2_[j]; }
        f2_[0] = fNew.x; f2_[1] = fNew.y; f2_[2] = fNew.z; f2_[3] = fNew.w;
        fsAprev = fsA;
        fsA = laneL ? fsNew.y : fsNew.x;
        fsB = laneL ? fsNew.x : fsNew.y;

        // ---- coarse advance on odd rows ----
        if (i & 1) {
            hLo0 = hHi0; hLo1 = hHi1; hLo2 = hHi2; hLo3 = hHi3; hLoA = hHiA; hLoB = hHiB;
            computeH(ucN, ucNs, hHi0, hHi1, hHi2, hHi3, hHiA, hHiB);
            loadUC((yl + 3) >> 1, ucN, ucNs);
        }

        // ---- v shift & compute row yl ----
        #pragma unroll
        for (int j = 0; j < 4; ++j) { v0_[j] = v1_[j]; v1_[j] = v2_[j]; }
        vsA_m2 = vsA_m1; vsA_m1 = vsA_c; vsB_m1 = vsB_c;
        {
            const float w0 = (i & 1) ? 1.5f : 0.5f;
            const float w1 = (i & 1) ? 0.5f : 1.5f;
            v2_[0] = w0 * hLo0 + w1 * hHi0 + cf * f2_[0];
            v2_[1] = w0 * hLo1 + w1 * hHi1 + cf * f2_[1];
            v2_[2] = w0 * hLo2 + w1 * hHi2 + cf * f2_[2];
            v2_[3] = w0 * hLo3 + w1 * hHi3 + cf * f2_[3];
            vsA_c = w0 * hLoA + w1 * hHiA + cf * fsA;
            vsB_c = w0 * hLoB + w1 * hHiB + cf * fsB;
            if (yl == 0 || yl == n - 1) {
                #pragma unroll
                for (int j = 0; j < 4; ++j) v2_[j] = cf * f2_[j];
                vsA_c = cf * fsA; vsB_c = cf * fsB;
            }
            if (gL) v2_[0] = cf * f2_[0];
            if (gR) v2_[3] = cf * f2_[3];
        }

        // ---- u shift & compute row yl-1 ----
        if (i >= 2) {
            const int yu = yl - 1;
            #pragma unroll
            for (int j = 0; j < 4; ++j) { u0_[j] = u1_[j]; u1_[j] = u2_[j]; }
            usA_p = usA_c;
            float vl = __shfl_up(v1_[3], 1);
            float vr = __shfl_down(v1_[0], 1);
            if (laneL) vl = vsA_m1;
            if (laneR) vr = vsA_m1;
            u2_[0] = v1_[0] + cf * f1_[0] + 0.2f * (v0_[0] + v2_[0] + vl      + v1_[1] - 4.f * v1_[0]);
            u2_[1] = v1_[1] + cf * f1_[1] + 0.2f * (v0_[1] + v2_[1] + v1_[0] + v1_[2] - 4.f * v1_[1]);
            u2_[2] = v1_[2] + cf * f1_[2] + 0.2f * (v0_[2] + v2_[2] + v1_[1] + v1_[3] - 4.f * v1_[2]);
            u2_[3] = v1_[3] + cf * f1_[3] + 0.2f * (v0_[3] + v2_[3] + v1_[2] + vr     - 4.f * v1_[3]);
            if (RESID && sideLane) {
                float vOwnE = laneL ? v1_[0] : v1_[3];
                usA_c = vsA_m1 + cf * fsAprev
                      + 0.2f * (vsA_m2 + vsA_c + vsB_m1 + vOwnE - 4.f * vsA_m1);
            }
            if (yu == 0 || yu == n - 1) {
                #pragma unroll
                for (int j = 0; j < 4; ++j) u2_[j] = v1_[j] + cf * f1_[j];
                if (RESID && sideLane) usA_c = vsA_m1 + cf * fsAprev;
            }
            if (gL) u2_[0] = v1_[0] + cf * f1_[0];
            if (gR) u2_[3] = v1_[3] + cf * f1_[3];
            if (i >= 3 && i <= 18) {
                *(float4*)(u + (size_t)yu * n + c0) =
                    make_float4(u2_[0], u2_[1], u2_[2], u2_[3]);
            }
        }

        // ---- fused residual row yl-2 ----
        if (RESID && i >= 4) {
            const int yr = yl - 2;
            float lf = __shfl_up(u1_[3], 1);
            float rt = __shfl_down(u1_[0], 1);
            if (laneL) lf = usA_p;
            if (laneR) rt = usA_p;
            float lap0 = u0_[0] + u2_[0] + lf      + u1_[1] - 4.f * u1_[0];
            float lap1 = u0_[1] + u2_[1] + u1_[0] + u1_[2] - 4.f * u1_[1];
            float lap2 = u0_[2] + u2_[2] + u1_[1] + u1_[3] - 4.f * u1_[2];
            float lap3 = u0_[3] + u2_[3] + u1_[2] + rt     - 4.f * u1_[3];
            float t0 = fabsf(f0_[0] - n2 * lap0);
            float t1 = fabsf(f0_[1] - n2 * lap1);
            float t2 = fabsf(f0_[2] - n2 * lap2);
            float t3 = fabsf(f0_[3] - n2 * lap3);
            if (yr == 0 || yr == n - 1) {
                t0 = fabsf(f0_[0]); t1 = fabsf(f0_[1]); t2 = fabsf(f0_[2]); t3 = fabsf(f0_[3]);
            }
            if (gL) t0 = fabsf(f0_[0]);
            if (gR) t3 = fabsf(f0_[3]);
            accT += t0 + t1 + t2 + t3;
            accF += fabsf(f0_[0]) + fabsf(f0_[1]) + fabsf(f0_[2]) + fabsf(f0_[3]);
        }
    }

    if (RESID) {
        double vT = (double)accT, vF = (double)accF;
        #pragma unroll
        for (int off = 32; off > 0; off >>= 1) {
            vT += __shfl_down(vT, off);
            vF += __shfl_down(vF, off);
        }
        if (lane == 0) {
            int widg = strip * nChunks + chunk;
            pT[widg] = vT;
            pF[widg] = vF;
        }
    }
}

__global__ void k_final(const double* __restrict__ pT, const double* __restrict__ pF,
                        int nb, float* __restrict__ out_res) {
    __shared__ double sT[256], sF[256];
    double tT = 0.0, tF = 0.0;
    for (int i = threadIdx.x; i < nb; i += 256) { tT += pT[i]; tF += pF[i]; }
    sT[threadIdx.x] = tT; sF[threadIdx.x] = tF;
    __syncthreads();
    for (int s = 128; s > 0; s >>= 1) {
        if (threadIdx.x < s) { sT[threadIdx.x] += sT[threadIdx.x + s]; sF[threadIdx.x] += sF[threadIdx.x + s]; }
        __syncthreads();
    }
    if (threadIdx.x == 0) *out_res = (float)(sT[0] / sF[0]);
}

extern "C" void kernel_launch(void* const* d_in, const int* in_sizes, int n_in,
                              void* d_out, int out_size, void* d_ws, size_t ws_size,
                              hipStream_t stream) {
    const float* f0 = (const float*)d_in[0];
    float* u0  = (float*)d_out;
    float* res = u0 + (size_t)N0 * N0;

    char* ws = (char*)d_ws;
    float* f1 = (float*)ws;                                            // N1*N1
    float* u1 = (float*)(ws + (size_t)N1 * N1 * 4);                    // N1*N1
    float* f2 = (float*)(ws + (size_t)2 * N1 * N1 * 4);                // N2*N2
    double* pT = (double*)(ws + (size_t)2 * N1 * N1 * 4 + (size_t)N2 * N2 * 4);
    const int NB = (N0 / 16) * (N0 / 256);                             // 256*16 = 4096 wave partials
    double* pF = pT + NB;

    const float c0 = -0.2f / ((float)N0 * (float)N0);
    const float c1 = -0.2f / ((float)N1 * (float)N1);
    const float c2 = -0.2f / ((float)N2 * (float)N2);

    k_res_restrict<<<dim3(N1 / 32, N1 / 32), 256, 0, stream>>>(f0, f1, N0, N1);
    k_res_restrict<<<dim3(N2 / 32, N2 / 32), 256, 0, stream>>>(f1, f2, N1, N2);
    // u1 = jacobi(c1*f1 + prolong(c2*f2), f1): strips 256x16 per wave
    k_smooth_strip<false><<<dim3(N1 / 256, N1 / 64), 256, 0, stream>>>(
        f1, f2, u1, N1, N2, c1, c2, nullptr, nullptr, N1 / 256);
    // u0 = jacobi(c0*f0 + prolong(u1), f0) + fused residual partials
    k_smooth_strip<true><<<dim3(N0 / 256, N0 / 64), 256, 0, stream>>>(
        f0, u1, u0, N0, N1, c0, 1.0f, pT, pF, N0 / 256);
    k_final<<<1, 256, 0, stream>>>(pT, pF, NB, res);
}

// Round 8
// 101.552 us; speedup vs baseline: 1.4629x; 1.4629x over previous
//
#include <hip/hip_runtime.h>

#define N0 4096
#define N1 2048
#define N2 1024

// ============ restrict: fc = restrict(f + 0.2*L(f)) — wide-row geometry ============
// Block: 256x16 fine tile, 256 threads = 64 lanes x 4 waves; thread = 4x4 fine = 2x2 coarse.
__global__ __launch_bounds__(256, 4) void k_res_restrict(const float* __restrict__ f,
                                                         float* __restrict__ fc,
                                                         int n, int nc) {
    const int tid = threadIdx.x;
    const int tx = tid & 63, ty = tid >> 6;
    const int fy0 = blockIdx.y * 16, fx0 = blockIdx.x * 256;
    const bool laneL = (tx == 0), laneR = (tx == 63);
    const bool edge = (blockIdx.x == 0) | (blockIdx.y == 0) |
                      (blockIdx.x == gridDim.x - 1) | (blockIdx.y == gridDim.y - 1);

    // window: fine rows fy0+4ty-1..+4, cols fx0+4tx-1..+4
    float fa[6][6];
    #pragma unroll
    for (int rr = 0; rr < 6; ++rr) {
        int gy = fy0 + 4 * ty - 1 + rr;
        gy = max(0, min(n - 1, gy));
        const float* rowp = f + (size_t)gy * n;
        float4 o = *(const float4*)(rowp + fx0 + 4 * tx);
        fa[rr][1] = o.x; fa[rr][2] = o.y; fa[rr][3] = o.z; fa[rr][4] = o.w;
        fa[rr][0] = __shfl_up(o.w, 1);
        fa[rr][5] = __shfl_down(o.x, 1);
        if (laneL) fa[rr][0] = rowp[max(0, fx0 - 1)];
        if (laneR) fa[rr][5] = rowp[min(n - 1, fx0 + 256)];
    }

    float rv[4][4];
    #pragma unroll
    for (int i = 0; i < 4; ++i) {
        #pragma unroll
        for (int j = 0; j < 4; ++j) {
            float c = fa[1 + i][1 + j];
            rv[i][j] = c + 0.2f * (fa[i][1 + j] + fa[2 + i][1 + j] +
                                   fa[1 + i][j] + fa[1 + i][2 + j] - 4.0f * c);
        }
    }
    if (edge) {
        #pragma unroll
        for (int i = 0; i < 4; ++i)
            #pragma unroll
            for (int j = 0; j < 4; ++j) {
                int gy = fy0 + 4 * ty + i, gx = fx0 + 4 * tx + j;
                if (gy == 0 || gy == n - 1 || gx == 0 || gx == n - 1)
                    rv[i][j] = fa[1 + i][1 + j];
            }
    }
    #pragma unroll
    for (int da = 0; da < 2; ++da) {
        float2 o;
        o.x = 0.25f * (rv[2*da][0] + rv[2*da][1] + rv[2*da+1][0] + rv[2*da+1][1]);
        o.y = 0.25f * (rv[2*da][2] + rv[2*da][3] + rv[2*da+1][2] + rv[2*da+1][3]);
        *(float2*)(fc + (size_t)(fy0 / 2 + 2 * ty + da) * nc + (fx0 / 2 + 2 * tx)) = o;
    }
}

// ====== fused smooth: u = jacobi(cf*f + cs*prolong(uc), f), optional residual ======
// Block: 256(x) x 8(y) outputs; 4 waves, wave = 2 rows; thread = 4 cols x 2 rows.
// All global accesses are wave-level 1KB contiguous bursts.
template <bool RESID>
__global__ __launch_bounds__(256, 4) void k_smooth_wide(
        const float* __restrict__ f, const float* __restrict__ uc,
        float* __restrict__ u, int n, int m, float cf, float cs,
        double* __restrict__ pT, double* __restrict__ pF) {
    __shared__ __align__(16) float su[RESID ? 10 : 1][260];  // u rows by0-1..by0+8, cols bx0..bx0+255
    __shared__ double sred[8];
    const int tid = threadIdx.x;
    const int tx = tid & 63, ty = tid >> 6;
    const int bx0 = blockIdx.x * 256, by0 = blockIdx.y * 8;
    const int A0 = by0 >> 1;
    const int C = (bx0 >> 1) + 2 * tx;
    const bool laneL = (tx == 0), laneR = (tx == 63);
    const bool edge = (blockIdx.x == 0) | (blockIdx.y == 0) |
                      (blockIdx.x == gridDim.x - 1) | (blockIdx.y == gridDim.y - 1);

    // ---- f window: rows by0+2ty-1..+2, cols bx0+4tx-1..+4 ----
    float fr[4][6];
    #pragma unroll
    for (int r = 0; r < 4; ++r) {
        int gy = by0 + 2 * ty - 1 + r;
        gy = max(0, min(n - 1, gy));
        const float* rowp = f + (size_t)gy * n;
        float4 o = *(const float4*)(rowp + bx0 + 4 * tx);
        fr[r][1] = o.x; fr[r][2] = o.y; fr[r][3] = o.z; fr[r][4] = o.w;
        fr[r][0] = __shfl_up(o.w, 1);
        fr[r][5] = __shfl_down(o.x, 1);
        if (laneL) fr[r][0] = rowp[max(0, bx0 - 1)];
        if (laneR) fr[r][5] = rowp[min(n - 1, bx0 + 256)];
    }

    // ---- coarse window: rows A0+ty-1..+1, cols C-1..C+2 (pre-scaled by cs) ----
    float cu[3][4];
    #pragma unroll
    for (int i = 0; i < 3; ++i) {
        int ga = A0 + ty - 1 + i;
        ga = max(0, min(m - 1, ga));
        const float* cp = uc + (size_t)ga * m;
        float2 o = *(const float2*)(cp + C);
        float l  = __shfl_up(o.y, 1);
        float rg = __shfl_down(o.x, 1);
        if (laneL) l  = cp[max(0, C - 1)];
        if (laneR) rg = cp[min(m - 1, C + 2)];
        cu[i][0] = cs * l; cu[i][1] = cs * o.x; cu[i][2] = cs * o.y; cu[i][3] = cs * rg;
    }

    // ---- horizontal interp ----
    float h[3][6];
    #pragma unroll
    for (int i = 0; i < 3; ++i) {
        h[i][0] = 1.5f * cu[i][0] + 0.5f * cu[i][1];
        h[i][1] = 0.5f * cu[i][0] + 1.5f * cu[i][1];
        h[i][2] = 1.5f * cu[i][1] + 0.5f * cu[i][2];
        h[i][3] = 0.5f * cu[i][1] + 1.5f * cu[i][2];
        h[i][4] = 1.5f * cu[i][2] + 0.5f * cu[i][3];
        h[i][5] = 0.5f * cu[i][2] + 1.5f * cu[i][3];
    }
    // ---- v = cf*f + prolong on rows by0+2ty-1..+2 ----
    float v[4][6];
    #pragma unroll
    for (int j = 0; j < 6; ++j) {
        v[0][j] = 1.5f * h[0][j] + 0.5f * h[1][j] + cf * fr[0][j];
        v[1][j] = 0.5f * h[0][j] + 1.5f * h[1][j] + cf * fr[1][j];
        v[2][j] = 1.5f * h[1][j] + 0.5f * h[2][j] + cf * fr[2][j];
        v[3][j] = 0.5f * h[1][j] + 1.5f * h[2][j] + cf * fr[3][j];
    }
    if (edge) {
        #pragma unroll
        for (int r = 0; r < 4; ++r)
            #pragma unroll
            for (int j = 0; j < 6; ++j) {
                int gy = by0 + 2 * ty - 1 + r, gx = bx0 + 4 * tx - 1 + j;
                if (gy == 0 || gy == n - 1 || gx == 0 || gx == n - 1) v[r][j] = cf * fr[r][j];
            }
    }
    // ---- u on own 2x4 ----
    float u2[2][4];
    #pragma unroll
    for (int rr = 0; rr < 2; ++rr)
        #pragma unroll
        for (int cc = 0; cc < 4; ++cc) {
            float vc = v[1 + rr][1 + cc];
            u2[rr][cc] = vc + cf * fr[1 + rr][1 + cc]
                       + 0.2f * (v[rr][1 + cc] + v[2 + rr][1 + cc] +
                                 v[1 + rr][cc] + v[1 + rr][2 + cc] - 4.0f * vc);
        }
    if (edge) {
        #pragma unroll
        for (int rr = 0; rr < 2; ++rr)
            #pragma unroll
            for (int cc = 0; cc < 4; ++cc) {
                int gy = by0 + 2 * ty + rr, gx = bx0 + 4 * tx + cc;
                if (gy == 0 || gy == n - 1 || gx == 0 || gx == n - 1)
                    u2[rr][cc] = v[1 + rr][1 + cc] + cf * fr[1 + rr][1 + cc];
            }
    }
    // ---- global store (1KB/row per wave) ----
    #pragma unroll
    for (int rr = 0; rr < 2; ++rr)
        *(float4*)(u + (size_t)(by0 + 2 * ty + rr) * n + (bx0 + 4 * tx)) =
            make_float4(u2[rr][0], u2[rr][1], u2[rr][2], u2[rr][3]);

    if (RESID) {
        float uHt[4], uHb[4], uL[2] = {0.f, 0.f}, uR[2] = {0.f, 0.f};
        // --- top halo u row (gy = by0-1), computed by wave ty==0 ---
        if (ty == 0) {
            const float* rowp = f + (size_t)max(0, by0 - 2) * n;
            float4 fm4 = *(const float4*)(rowp + bx0 + 4 * tx);
            const float* crow = uc + (size_t)max(0, A0 - 2) * m;
            float2 o = *(const float2*)(crow + C);
            float l  = __shfl_up(o.y, 1);
            float rg = __shfl_down(o.x, 1);
            if (laneL) l  = crow[max(0, C - 1)];
            if (laneR) rg = crow[min(m - 1, C + 2)];
            l *= cs; rg *= cs;
            float ox = cs * o.x, oy = cs * o.y;
            float hm[4] = { 0.5f * l + 1.5f * ox, 1.5f * ox + 0.5f * oy,
                            0.5f * ox + 1.5f * oy, 1.5f * oy + 0.5f * rg };
            float fmv[4] = { fm4.x, fm4.y, fm4.z, fm4.w };
            float vm[4];
            #pragma unroll
            for (int cc = 0; cc < 4; ++cc) vm[cc] = 0.5f * hm[cc] + 1.5f * h[0][1 + cc] + cf * fmv[cc];
            if (edge) {
                #pragma unroll
                for (int cc = 0; cc < 4; ++cc) {
                    int gx = bx0 + 4 * tx + cc;
                    if (gx == 0 || gx == n - 1) vm[cc] = cf * fmv[cc];
                }
            }
            #pragma unroll
            for (int cc = 0; cc < 4; ++cc) {
                float vc = v[0][1 + cc];
                uHt[cc] = vc + cf * fr[0][1 + cc]
                        + 0.2f * (vm[cc] + v[1][1 + cc] + v[0][cc] + v[0][2 + cc] - 4.0f * vc);
            }
            if (edge) {
                #pragma unroll
                for (int cc = 0; cc < 4; ++cc) {
                    int gx = bx0 + 4 * tx + cc;
                    if (gx == 0 || gx == n - 1) uHt[cc] = v[0][1 + cc] + cf * fr[0][1 + cc];
                }
            }
            *(float4*)&su[0][4 * tx] = make_float4(uHt[0], uHt[1], uHt[2], uHt[3]);
        }
        // --- bottom halo u row (gy = by0+8), computed by wave ty==3 ---
        if (ty == 3) {
            const float* rowp = f + (size_t)min(n - 1, by0 + 9) * n;
            float4 fp4 = *(const float4*)(rowp + bx0 + 4 * tx);
            const float* crow = uc + (size_t)min(m - 1, A0 + 5) * m;
            float2 o = *(const float2*)(crow + C);
            float l  = __shfl_up(o.y, 1);
            float rg = __shfl_down(o.x, 1);
            if (laneL) l  = crow[max(0, C - 1)];
            if (laneR) rg = crow[min(m - 1, C + 2)];
            l *= cs; rg *= cs;
            float ox = cs * o.x, oy = cs * o.y;
            float hp[4] = { 0.5f * l + 1.5f * ox, 1.5f * ox + 0.5f * oy,
                            0.5f * ox + 1.5f * oy, 1.5f * oy + 0.5f * rg };
            float fpv[4] = { fp4.x, fp4.y, fp4.z, fp4.w };
            float vp[4];
            #pragma unroll
            for (int cc = 0; cc < 4; ++cc) vp[cc] = 1.5f * h[2][1 + cc] + 0.5f * hp[cc] + cf * fpv[cc];
            if (edge) {
                #pragma unroll
                for (int cc = 0; cc < 4; ++cc) {
                    int gx = bx0 + 4 * tx + cc;
                    if (gx == 0 || gx == n - 1) vp[cc] = cf * fpv[cc];
                }
            }
            #pragma unroll
            for (int cc = 0; cc < 4; ++cc) {
                float vc = v[3][1 + cc];
                uHb[cc] = vc + cf * fr[3][1 + cc]
                        + 0.2f * (v[2][1 + cc] + vp[cc] + v[3][cc] + v[3][2 + cc] - 4.0f * vc);
            }
            if (edge) {
                #pragma unroll
                for (int cc = 0; cc < 4; ++cc) {
                    int gx = bx0 + 4 * tx + cc;
                    if (gx == 0 || gx == n - 1) uHb[cc] = v[3][1 + cc] + cf * fr[3][1 + cc];
                }
            }
            *(float4*)&su[9][4 * tx] = make_float4(uHb[0], uHb[1], uHb[2], uHb[3]);
        }
        // --- left halo u col (gx = bx0-1), lane 0 of each wave ---
        if (laneL) {
            float cL[3], fL[2];
            #pragma unroll
            for (int i = 0; i < 3; ++i) {
                int ga = A0 + ty - 1 + i;
                ga = max(0, min(m - 1, ga));
                cL[i] = uc[(size_t)ga * m + max(0, C - 2)];
            }
            #pragma unroll
            for (int k = 0; k < 2; ++k)
                fL[k] = f[(size_t)(by0 + 2 * ty + k) * n + max(0, bx0 - 2)];
            float hL[3];
            #pragma unroll
            for (int i = 0; i < 3; ++i) hL[i] = 0.5f * cs * cL[i] + 1.5f * cu[i][0];
            float vL[2] = { 0.5f * hL[0] + 1.5f * hL[1] + cf * fL[0],
                            1.5f * hL[1] + 0.5f * hL[2] + cf * fL[1] };
            if (edge) {
                #pragma unroll
                for (int k = 0; k < 2; ++k) {
                    int gy = by0 + 2 * ty + k;
                    if (gy == 0 || gy == n - 1 || bx0 - 2 == 0) vL[k] = cf * fL[k];
                }
            }
            #pragma unroll
            for (int rr = 0; rr < 2; ++rr) {
                float vc = v[1 + rr][0];
                uL[rr] = vc + cf * fr[1 + rr][0]
                       + 0.2f * (v[rr][0] + v[2 + rr][0] + vL[rr] + v[1 + rr][1] - 4.0f * vc);
                if (edge) {
                    int gy = by0 + 2 * ty + rr;
                    if (gy == 0 || gy == n - 1) uL[rr] = vc + cf * fr[1 + rr][0];
                }
            }
        }
        // --- right halo u col (gx = bx0+256), lane 63 of each wave ---
        if (laneR) {
            float cR[3], fR[2];
            #pragma unroll
            for (int i = 0; i < 3; ++i) {
                int ga = A0 + ty - 1 + i;
                ga = max(0, min(m - 1, ga));
                cR[i] = uc[(size_t)ga * m + min(m - 1, C + 3)];
            }
            #pragma unroll
            for (int k = 0; k < 2; ++k)
                fR[k] = f[(size_t)(by0 + 2 * ty + k) * n + min(n - 1, bx0 + 257)];
            float hR[3];
            #pragma unroll
            for (int i = 0; i < 3; ++i) hR[i] = 1.5f * cu[i][3] + 0.5f * cs * cR[i];
            float vR[2] = { 0.5f * hR[0] + 1.5f * hR[1] + cf * fR[0],
                            1.5f * hR[1] + 0.5f * hR[2] + cf * fR[1] };
            if (edge) {
                #pragma unroll
                for (int k = 0; k < 2; ++k) {
                    int gy = by0 + 2 * ty + k;
                    if (gy == 0 || gy == n - 1 || bx0 + 257 == n - 1) vR[k] = cf * fR[k];
                }
            }
            #pragma unroll
            for (int rr = 0; rr < 2; ++rr) {
                float vc = v[1 + rr][5];
                uR[rr] = vc + cf * fr[1 + rr][5]
                       + 0.2f * (v[rr][5] + v[2 + rr][5] + v[1 + rr][4] + vR[rr] - 4.0f * vc);
                if (edge) {
                    int gy = by0 + 2 * ty + rr;
                    if (gy == 0 || gy == n - 1) uR[rr] = vc + cf * fr[1 + rr][5];
                }
            }
        }
        // --- u exchange via LDS (own rows) ---
        #pragma unroll
        for (int rr = 0; rr < 2; ++rr)
            *(float4*)&su[2 * ty + 1 + rr][4 * tx] =
                make_float4(u2[rr][0], u2[rr][1], u2[rr][2], u2[rr][3]);
        __syncthreads();
        float4 tv = *(const float4*)&su[2 * ty][4 * tx];
        float4 bv = *(const float4*)&su[2 * ty + 3][4 * tx];
        float ta[4] = { tv.x, tv.y, tv.z, tv.w };
        float ba[4] = { bv.x, bv.y, bv.z, bv.w };
        float lft[2], rgt[2];
        lft[0] = __shfl_up(u2[0][3], 1);  lft[1] = __shfl_up(u2[1][3], 1);
        rgt[0] = __shfl_down(u2[0][0], 1); rgt[1] = __shfl_down(u2[1][0], 1);
        if (laneL) { lft[0] = uL[0]; lft[1] = uL[1]; }
        if (laneR) { rgt[0] = uR[0]; rgt[1] = uR[1]; }
        const float n2 = (float)n * (float)n;
        float accT = 0.0f, accF = 0.0f;
        #pragma unroll
        for (int rr = 0; rr < 2; ++rr)
            #pragma unroll
            for (int cc = 0; cc < 4; ++cc) {
                float up = (rr == 0) ? ta[cc] : u2[0][cc];
                float dn = (rr == 1) ? ba[cc] : u2[1][cc];
                float lf = (cc == 0) ? lft[rr] : u2[rr][cc - 1];
                float rt = (cc == 3) ? rgt[rr] : u2[rr][cc + 1];
                float uu = u2[rr][cc];
                float fij = fr[1 + rr][1 + cc];
                float L = up + dn + lf + rt - 4.0f * uu;
                float t = fabsf(fij - n2 * L);
                if (edge) {
                    int gy = by0 + 2 * ty + rr, gx = bx0 + 4 * tx + cc;
                    if (gy == 0 || gy == n - 1 || gx == 0 || gx == n - 1) t = fabsf(fij);
                }
                accT += t;
                accF += fabsf(fij);
            }
        // --- reduction: wave shuffle then 4-wave combine ---
        double vT = (double)accT, vF = (double)accF;
        #pragma unroll
        for (int off = 32; off > 0; off >>= 1) {
            vT += __shfl_down(vT, off);
            vF += __shfl_down(vF, off);
        }
        if (tx == 0) { sred[ty] = vT; sred[ty + 4] = vF; }
        __syncthreads();
        if (tid == 0) {
            int bid = blockIdx.y * gridDim.x + blockIdx.x;
            pT[bid] = sred[0] + sred[1] + sred[2] + sred[3];
            pF[bid] = sred[4] + sred[5] + sred[6] + sred[7];
        }
    }
}

__global__ void k_final(const double* __restrict__ pT, const double* __restrict__ pF,
                        int nb, float* __restrict__ out_res) {
    __shared__ double sT[256], sF[256];
    double tT = 0.0, tF = 0.0;
    for (int i = threadIdx.x; i < nb; i += 256) { tT += pT[i]; tF += pF[i]; }
    sT[threadIdx.x] = tT; sF[threadIdx.x] = tF;
    __syncthreads();
    for (int s = 128; s > 0; s >>= 1) {
        if (threadIdx.x < s) { sT[threadIdx.x] += sT[threadIdx.x + s]; sF[threadIdx.x] += sF[threadIdx.x + s]; }
        __syncthreads();
    }
    if (threadIdx.x == 0) *out_res = (float)(sT[0] / sF[0]);
}

extern "C" void kernel_launch(void* const* d_in, const int* in_sizes, int n_in,
                              void* d_out, int out_size, void* d_ws, size_t ws_size,
                              hipStream_t stream) {
    const float* f0 = (const float*)d_in[0];
    float* u0  = (float*)d_out;
    float* res = u0 + (size_t)N0 * N0;

    char* ws = (char*)d_ws;
    float* f1 = (float*)ws;                                            // N1*N1
    float* u1 = (float*)(ws + (size_t)N1 * N1 * 4);                    // N1*N1
    float* f2 = (float*)(ws + (size_t)2 * N1 * N1 * 4);                // N2*N2
    double* pT = (double*)(ws + (size_t)2 * N1 * N1 * 4 + (size_t)N2 * N2 * 4);
    const int NB = (N0 / 256) * (N0 / 8);                              // 16*512 = 8192
    double* pF = pT + NB;

    const float c0 = -0.2f / ((float)N0 * (float)N0);
    const float c1 = -0.2f / ((float)N1 * (float)N1);
    const float c2 = -0.2f / ((float)N2 * (float)N2);

    k_res_restrict<<<dim3(N0 / 256, N0 / 16), 256, 0, stream>>>(f0, f1, N0, N1);
    k_res_restrict<<<dim3(N1 / 256, N1 / 16), 256, 0, stream>>>(f1, f2, N1, N2);
    k_smooth_wide<false><<<dim3(N1 / 256, N1 / 8), 256, 0, stream>>>(
        f1, f2, u1, N1, N2, c1, c2, nullptr, nullptr);
    k_smooth_wide<true><<<dim3(N0 / 256, N0 / 8), 256, 0, stream>>>(
        f0, u1, u0, N0, N1, c0, 1.0f, pT, pF);
    k_final<<<1, 256, 0, stream>>>(pT, pF, NB, res);
}

// Round 9
// 86.356 us; speedup vs baseline: 1.7203x; 1.1760x over previous
//
#include <hip/hip_runtime.h>

#define N0 4096
#define N1 2048
#define N2 1024

// ============ restrict: fc = restrict(f + 0.2*L(f)) — zero LDS, loads hoisted ============
// Block: 256x16 fine tile, 256 threads = 64 lanes x 4 waves; thread = 4x4 fine = 2x2 coarse.
__global__ __launch_bounds__(256, 4) void k_res_restrict(const float* __restrict__ f,
                                                         float* __restrict__ fc,
                                                         int n, int nc) {
    const int tid = threadIdx.x;
    const int tx = tid & 63, ty = tid >> 6;
    const int fy0 = blockIdx.y * 16, fx0 = blockIdx.x * 256;
    const bool laneL = (tx == 0), laneR = (tx == 63);
    const bool edge = (blockIdx.x == 0) | (blockIdx.y == 0) |
                      (blockIdx.x == gridDim.x - 1) | (blockIdx.y == gridDim.y - 1);

    // ---- phase 1: all loads ----
    float4 o4[6]; float os[6];
    #pragma unroll
    for (int rr = 0; rr < 6; ++rr) {
        int gy = max(0, min(n - 1, fy0 + 4 * ty - 1 + rr));
        const float* rowp = f + (size_t)gy * n;
        o4[rr] = *(const float4*)(rowp + fx0 + 4 * tx);
        if (laneL) os[rr] = rowp[max(0, fx0 - 1)];
        if (laneR) os[rr] = rowp[min(n - 1, fx0 + 256)];
    }
    // ---- phase 2: expand + compute ----
    float fa[6][6];
    #pragma unroll
    for (int rr = 0; rr < 6; ++rr) {
        fa[rr][1] = o4[rr].x; fa[rr][2] = o4[rr].y; fa[rr][3] = o4[rr].z; fa[rr][4] = o4[rr].w;
        fa[rr][0] = __shfl_up(o4[rr].w, 1);
        fa[rr][5] = __shfl_down(o4[rr].x, 1);
        if (laneL) fa[rr][0] = os[rr];
        if (laneR) fa[rr][5] = os[rr];
    }
    float rv[4][4];
    #pragma unroll
    for (int i = 0; i < 4; ++i) {
        #pragma unroll
        for (int j = 0; j < 4; ++j) {
            float c = fa[1 + i][1 + j];
            rv[i][j] = c + 0.2f * (fa[i][1 + j] + fa[2 + i][1 + j] +
                                   fa[1 + i][j] + fa[1 + i][2 + j] - 4.0f * c);
        }
    }
    if (edge) {
        #pragma unroll
        for (int i = 0; i < 4; ++i)
            #pragma unroll
            for (int j = 0; j < 4; ++j) {
                int gy = fy0 + 4 * ty + i, gx = fx0 + 4 * tx + j;
                if (gy == 0 || gy == n - 1 || gx == 0 || gx == n - 1)
                    rv[i][j] = fa[1 + i][1 + j];
            }
    }
    #pragma unroll
    for (int da = 0; da < 2; ++da) {
        float2 o;
        o.x = 0.25f * (rv[2*da][0] + rv[2*da][1] + rv[2*da+1][0] + rv[2*da+1][1]);
        o.y = 0.25f * (rv[2*da][2] + rv[2*da][3] + rv[2*da+1][2] + rv[2*da+1][3]);
        *(float2*)(fc + (size_t)(fy0 / 2 + 2 * ty + da) * nc + (fx0 / 2 + 2 * tx)) = o;
    }
}

// ====== fused smooth: u = jacobi(cf*f + cs*prolong(uc), f), optional residual ======
// Block: 256(x) x 16(y) outputs; 512 threads = 8 waves x 2 rows; thread = 4 cols x 2 rows.
// ALL global loads issued in phase 1; one barrier (RESID u-halo exchange) only.
template <bool RESID>
__global__ __launch_bounds__(512, 4) void k_smooth_wide(
        const float* __restrict__ f, const float* __restrict__ uc,
        float* __restrict__ u, int n, int m, float cf, float cs,
        double* __restrict__ pT, double* __restrict__ pF) {
    __shared__ __align__(16) float su[RESID ? 18 : 1][260];  // u rows by0-1..by0+16
    __shared__ double sred[16];
    const int tid = threadIdx.x;
    const int tx = tid & 63, ty = tid >> 6;           // ty 0..7
    const int bx0 = blockIdx.x * 256, by0 = blockIdx.y * 16;
    const int Y  = by0 + 2 * ty;                      // first own row
    const int A0 = by0 >> 1;
    const int A  = A0 + ty;
    const int C  = (bx0 >> 1) + 2 * tx;
    const bool laneL = (tx == 0), laneR = (tx == 63);
    const bool edge = (blockIdx.x == 0) | (blockIdx.y == 0) |
                      (blockIdx.x == gridDim.x - 1) | (blockIdx.y == gridDim.y - 1);

    // ================= phase 1: issue ALL global loads =================
    float4 f4[4]; float fs[4];
    #pragma unroll
    for (int r = 0; r < 4; ++r) {
        int gy = max(0, min(n - 1, Y - 1 + r));
        const float* rowp = f + (size_t)gy * n;
        f4[r] = *(const float4*)(rowp + bx0 + 4 * tx);
        if (laneL) fs[r] = rowp[max(0, bx0 - 1)];
        if (laneR) fs[r] = rowp[min(n - 1, bx0 + 256)];
    }
    float2 c2[3]; float csd[3];
    #pragma unroll
    for (int i = 0; i < 3; ++i) {
        int ga = max(0, min(m - 1, A - 1 + i));
        const float* cp = uc + (size_t)ga * m;
        c2[i] = *(const float2*)(cp + C);
        if (laneL) csd[i] = cp[max(0, C - 1)];
        if (laneR) csd[i] = cp[min(m - 1, C + 2)];
    }
    float4 fH4 = make_float4(0.f, 0.f, 0.f, 0.f); float fHs = 0.f;
    float2 cH2 = make_float2(0.f, 0.f);            float cHs = 0.f;
    float fsd2[2] = {0.f, 0.f}; float csd2[3] = {0.f, 0.f, 0.f};
    if (RESID) {
        if (ty == 0) {
            const float* rowp = f + (size_t)max(0, by0 - 2) * n;
            fH4 = *(const float4*)(rowp + bx0 + 4 * tx);
            if (laneL) fHs = rowp[max(0, bx0 - 1)];
            if (laneR) fHs = rowp[min(n - 1, bx0 + 256)];
            const float* cp = uc + (size_t)max(0, A0 - 2) * m;
            cH2 = *(const float2*)(cp + C);
            if (laneL) cHs = cp[max(0, C - 1)];
            if (laneR) cHs = cp[min(m - 1, C + 2)];
        }
        if (ty == 7) {
            const float* rowp = f + (size_t)min(n - 1, by0 + 17) * n;
            fH4 = *(const float4*)(rowp + bx0 + 4 * tx);
            if (laneL) fHs = rowp[max(0, bx0 - 1)];
            if (laneR) fHs = rowp[min(n - 1, bx0 + 256)];
            const float* cp = uc + (size_t)min(m - 1, A0 + 9) * m;
            cH2 = *(const float2*)(cp + C);
            if (laneL) cHs = cp[max(0, C - 1)];
            if (laneR) cHs = cp[min(m - 1, C + 2)];
        }
        if (laneL) {
            #pragma unroll
            for (int i = 0; i < 3; ++i) {
                int ga = max(0, min(m - 1, A - 1 + i));
                csd2[i] = uc[(size_t)ga * m + max(0, C - 2)];
            }
            #pragma unroll
            for (int k = 0; k < 2; ++k)
                fsd2[k] = f[(size_t)(Y + k) * n + max(0, bx0 - 2)];
        }
        if (laneR) {
            #pragma unroll
            for (int i = 0; i < 3; ++i) {
                int ga = max(0, min(m - 1, A - 1 + i));
                csd2[i] = uc[(size_t)ga * m + min(m - 1, C + 3)];
            }
            #pragma unroll
            for (int k = 0; k < 2; ++k)
                fsd2[k] = f[(size_t)(Y + k) * n + min(n - 1, bx0 + 257)];
        }
    }

    // ================= phase 2: compute =================
    float fr[4][6];
    #pragma unroll
    for (int r = 0; r < 4; ++r) {
        fr[r][1] = f4[r].x; fr[r][2] = f4[r].y; fr[r][3] = f4[r].z; fr[r][4] = f4[r].w;
        fr[r][0] = __shfl_up(f4[r].w, 1);
        fr[r][5] = __shfl_down(f4[r].x, 1);
        if (laneL) fr[r][0] = fs[r];
        if (laneR) fr[r][5] = fs[r];
    }
    float cu[3][4];
    #pragma unroll
    for (int i = 0; i < 3; ++i) {
        float l  = __shfl_up(c2[i].y, 1);
        float rg = __shfl_down(c2[i].x, 1);
        if (laneL) l  = csd[i];
        if (laneR) rg = csd[i];
        cu[i][0] = cs * l; cu[i][1] = cs * c2[i].x; cu[i][2] = cs * c2[i].y; cu[i][3] = cs * rg;
    }
    float h[3][6];
    #pragma unroll
    for (int i = 0; i < 3; ++i) {
        h[i][0] = 1.5f * cu[i][0] + 0.5f * cu[i][1];
        h[i][1] = 0.5f * cu[i][0] + 1.5f * cu[i][1];
        h[i][2] = 1.5f * cu[i][1] + 0.5f * cu[i][2];
        h[i][3] = 0.5f * cu[i][1] + 1.5f * cu[i][2];
        h[i][4] = 1.5f * cu[i][2] + 0.5f * cu[i][3];
        h[i][5] = 0.5f * cu[i][2] + 1.5f * cu[i][3];
    }
    float v[4][6];
    #pragma unroll
    for (int j = 0; j < 6; ++j) {
        v[0][j] = 1.5f * h[0][j] + 0.5f * h[1][j] + cf * fr[0][j];
        v[1][j] = 0.5f * h[0][j] + 1.5f * h[1][j] + cf * fr[1][j];
        v[2][j] = 1.5f * h[1][j] + 0.5f * h[2][j] + cf * fr[2][j];
        v[3][j] = 0.5f * h[1][j] + 1.5f * h[2][j] + cf * fr[3][j];
    }
    if (edge) {
        #pragma unroll
        for (int r = 0; r < 4; ++r)
            #pragma unroll
            for (int j = 0; j < 6; ++j) {
                int gy = Y - 1 + r, gx = bx0 + 4 * tx - 1 + j;
                if (gy == 0 || gy == n - 1 || gx == 0 || gx == n - 1) v[r][j] = cf * fr[r][j];
            }
    }
    float u2[2][4];
    #pragma unroll
    for (int rr = 0; rr < 2; ++rr)
        #pragma unroll
        for (int cc = 0; cc < 4; ++cc) {
            float vc = v[1 + rr][1 + cc];
            u2[rr][cc] = vc + cf * fr[1 + rr][1 + cc]
                       + 0.2f * (v[rr][1 + cc] + v[2 + rr][1 + cc] +
                                 v[1 + rr][cc] + v[1 + rr][2 + cc] - 4.0f * vc);
        }
    if (edge) {
        #pragma unroll
        for (int rr = 0; rr < 2; ++rr)
            #pragma unroll
            for (int cc = 0; cc < 4; ++cc) {
                int gy = Y + rr, gx = bx0 + 4 * tx + cc;
                if (gy == 0 || gy == n - 1 || gx == 0 || gx == n - 1)
                    u2[rr][cc] = v[1 + rr][1 + cc] + cf * fr[1 + rr][1 + cc];
            }
    }
    #pragma unroll
    for (int rr = 0; rr < 2; ++rr)
        *(float4*)(u + (size_t)(Y + rr) * n + (bx0 + 4 * tx)) =
            make_float4(u2[rr][0], u2[rr][1], u2[rr][2], u2[rr][3]);

    if (RESID) {
        // ---- halo u rows (preloaded data, no new global loads) ----
        if (ty == 0) {
            float l  = __shfl_up(cH2.y, 1);
            float rg = __shfl_down(cH2.x, 1);
            if (laneL) l  = cHs;
            if (laneR) rg = cHs;
            l *= cs; rg *= cs;
            float ox = cs * cH2.x, oy = cs * cH2.y;
            float hm[4] = { 0.5f * l + 1.5f * ox, 1.5f * ox + 0.5f * oy,
                            0.5f * ox + 1.5f * oy, 1.5f * oy + 0.5f * rg };
            float fmv[4] = { fH4.x, fH4.y, fH4.z, fH4.w };
            float vm[4], uHt[4];
            #pragma unroll
            for (int cc = 0; cc < 4; ++cc) vm[cc] = 0.5f * hm[cc] + 1.5f * h[0][1 + cc] + cf * fmv[cc];
            if (edge) {
                #pragma unroll
                for (int cc = 0; cc < 4; ++cc) {
                    int gx = bx0 + 4 * tx + cc;
                    if (gx == 0 || gx == n - 1) vm[cc] = cf * fmv[cc];
                }
            }
            #pragma unroll
            for (int cc = 0; cc < 4; ++cc) {
                float vc = v[0][1 + cc];
                uHt[cc] = vc + cf * fr[0][1 + cc]
                        + 0.2f * (vm[cc] + v[1][1 + cc] + v[0][cc] + v[0][2 + cc] - 4.0f * vc);
            }
            if (edge) {
                #pragma unroll
                for (int cc = 0; cc < 4; ++cc) {
                    int gx = bx0 + 4 * tx + cc;
                    if (gx == 0 || gx == n - 1) uHt[cc] = v[0][1 + cc] + cf * fr[0][1 + cc];
                }
            }
            *(float4*)&su[0][4 * tx] = make_float4(uHt[0], uHt[1], uHt[2], uHt[3]);
        }
        if (ty == 7) {
            float l  = __shfl_up(cH2.y, 1);
            float rg = __shfl_down(cH2.x, 1);
            if (laneL) l  = cHs;
            if (laneR) rg = cHs;
            l *= cs; rg *= cs;
            float ox = cs * cH2.x, oy = cs * cH2.y;
            float hp[4] = { 0.5f * l + 1.5f * ox, 1.5f * ox + 0.5f * oy,
                            0.5f * ox + 1.5f * oy, 1.5f * oy + 0.5f * rg };
            float fpv[4] = { fH4.x, fH4.y, fH4.z, fH4.w };
            float vp[4], uHb[4];
            #pragma unroll
            for (int cc = 0; cc < 4; ++cc) vp[cc] = 1.5f * h[2][1 + cc] + 0.5f * hp[cc] + cf * fpv[cc];
            if (edge) {
                #pragma unroll
                for (int cc = 0; cc < 4; ++cc) {
                    int gx = bx0 + 4 * tx + cc;
                    if (gx == 0 || gx == n - 1) vp[cc] = cf * fpv[cc];
                }
            }
            #pragma unroll
            for (int cc = 0; cc < 4; ++cc) {
                float vc = v[3][1 + cc];
                uHb[cc] = vc + cf * fr[3][1 + cc]
                        + 0.2f * (v[2][1 + cc] + vp[cc] + v[3][cc] + v[3][2 + cc] - 4.0f * vc);
            }
            if (edge) {
                #pragma unroll
                for (int cc = 0; cc < 4; ++cc) {
                    int gx = bx0 + 4 * tx + cc;
                    if (gx == 0 || gx == n - 1) uHb[cc] = v[3][1 + cc] + cf * fr[3][1 + cc];
                }
            }
            *(float4*)&su[17][4 * tx] = make_float4(uHb[0], uHb[1], uHb[2], uHb[3]);
        }
        // ---- side columns ----
        float uL[2] = {0.f, 0.f}, uR[2] = {0.f, 0.f};
        if (laneL) {
            float hL[3];
            #pragma unroll
            for (int i = 0; i < 3; ++i) hL[i] = 0.5f * cs * csd2[i] + 1.5f * cu[i][0];
            float vL[2] = { 0.5f * hL[0] + 1.5f * hL[1] + cf * fsd2[0],
                            1.5f * hL[1] + 0.5f * hL[2] + cf * fsd2[1] };
            if (edge) {
                #pragma unroll
                for (int k = 0; k < 2; ++k) {
                    int gy = Y + k;
                    if (gy == 0 || gy == n - 1) vL[k] = cf * fsd2[k];
                }
            }
            #pragma unroll
            for (int rr = 0; rr < 2; ++rr) {
                float vc = v[1 + rr][0];
                uL[rr] = vc + cf * fr[1 + rr][0]
                       + 0.2f * (v[rr][0] + v[2 + rr][0] + vL[rr] + v[1 + rr][1] - 4.0f * vc);
                if (edge) {
                    int gy = Y + rr;
                    if (gy == 0 || gy == n - 1) uL[rr] = vc + cf * fr[1 + rr][0];
                }
            }
        }
        if (laneR) {
            float hR[3];
            #pragma unroll
            for (int i = 0; i < 3; ++i) hR[i] = 1.5f * cu[i][3] + 0.5f * cs * csd2[i];
            float vR[2] = { 0.5f * hR[0] + 1.5f * hR[1] + cf * fsd2[0],
                            1.5f * hR[1] + 0.5f * hR[2] + cf * fsd2[1] };
            if (edge) {
                #pragma unroll
                for (int k = 0; k < 2; ++k) {
                    int gy = Y + k;
                    if (gy == 0 || gy == n - 1) vR[k] = cf * fsd2[k];
                }
            }
            #pragma unroll
            for (int rr = 0; rr < 2; ++rr) {
                float vc = v[1 + rr][5];
                uR[rr] = vc + cf * fr[1 + rr][5]
                       + 0.2f * (v[rr][5] + v[2 + rr][5] + v[1 + rr][4] + vR[rr] - 4.0f * vc);
                if (edge) {
                    int gy = Y + rr;
                    if (gy == 0 || gy == n - 1) uR[rr] = vc + cf * fr[1 + rr][5];
                }
            }
        }
        // ---- u exchange (one barrier) ----
        #pragma unroll
        for (int rr = 0; rr < 2; ++rr)
            *(float4*)&su[2 * ty + 1 + rr][4 * tx] =
                make_float4(u2[rr][0], u2[rr][1], u2[rr][2], u2[rr][3]);
        __syncthreads();
        float4 tv = *(const float4*)&su[2 * ty][4 * tx];
        float4 bv = *(const float4*)&su[2 * ty + 3][4 * tx];
        float ta[4] = { tv.x, tv.y, tv.z, tv.w };
        float ba[4] = { bv.x, bv.y, bv.z, bv.w };
        float lft[2], rgt[2];
        lft[0] = __shfl_up(u2[0][3], 1);   lft[1] = __shfl_up(u2[1][3], 1);
        rgt[0] = __shfl_down(u2[0][0], 1); rgt[1] = __shfl_down(u2[1][0], 1);
        if (laneL) { lft[0] = uL[0]; lft[1] = uL[1]; }
        if (laneR) { rgt[0] = uR[0]; rgt[1] = uR[1]; }
        const float n2 = (float)n * (float)n;
        float accT = 0.0f, accF = 0.0f;
        #pragma unroll
        for (int rr = 0; rr < 2; ++rr)
            #pragma unroll
            for (int cc = 0; cc < 4; ++cc) {
                float up = (rr == 0) ? ta[cc] : u2[0][cc];
                float dn = (rr == 1) ? ba[cc] : u2[1][cc];
                float lf = (cc == 0) ? lft[rr] : u2[rr][cc - 1];
                float rt = (cc == 3) ? rgt[rr] : u2[rr][cc + 1];
                float uu = u2[rr][cc];
                float fij = fr[1 + rr][1 + cc];
                float L = up + dn + lf + rt - 4.0f * uu;
                float t = fabsf(fij - n2 * L);
                if (edge) {
                    int gy = Y + rr, gx = bx0 + 4 * tx + cc;
                    if (gy == 0 || gy == n - 1 || gx == 0 || gx == n - 1) t = fabsf(fij);
                }
                accT += t;
                accF += fabsf(fij);
            }
        double vT = (double)accT, vF = (double)accF;
        #pragma unroll
        for (int off = 32; off > 0; off >>= 1) {
            vT += __shfl_down(vT, off);
            vF += __shfl_down(vF, off);
        }
        if (tx == 0) { sred[ty] = vT; sred[8 + ty] = vF; }
        __syncthreads();
        if (tid == 0) {
            double sT = 0.0, sF = 0.0;
            #pragma unroll
            for (int w = 0; w < 8; ++w) { sT += sred[w]; sF += sred[8 + w]; }
            int bid = blockIdx.y * gridDim.x + blockIdx.x;
            pT[bid] = sT;
            pF[bid] = sF;
        }
    }
}

__global__ void k_final(const double* __restrict__ pT, const double* __restrict__ pF,
                        int nb, float* __restrict__ out_res) {
    __shared__ double sT[256], sF[256];
    double tT = 0.0, tF = 0.0;
    for (int i = threadIdx.x; i < nb; i += 256) { tT += pT[i]; tF += pF[i]; }
    sT[threadIdx.x] = tT; sF[threadIdx.x] = tF;
    __syncthreads();
    for (int s = 128; s > 0; s >>= 1) {
        if (threadIdx.x < s) { sT[threadIdx.x] += sT[threadIdx.x + s]; sF[threadIdx.x] += sF[threadIdx.x + s]; }
        __syncthreads();
    }
    if (threadIdx.x == 0) *out_res = (float)(sT[0] / sF[0]);
}

extern "C" void kernel_launch(void* const* d_in, const int* in_sizes, int n_in,
                              void* d_out, int out_size, void* d_ws, size_t ws_size,
                              hipStream_t stream) {
    const float* f0 = (const float*)d_in[0];
    float* u0  = (float*)d_out;
    float* res = u0 + (size_t)N0 * N0;

    char* ws = (char*)d_ws;
    float* f1 = (float*)ws;                                            // N1*N1
    float* u1 = (float*)(ws + (size_t)N1 * N1 * 4);                    // N1*N1
    float* f2 = (float*)(ws + (size_t)2 * N1 * N1 * 4);                // N2*N2
    double* pT = (double*)(ws + (size_t)2 * N1 * N1 * 4 + (size_t)N2 * N2 * 4);
    const int NB = (N0 / 256) * (N0 / 16);                             // 4096 blocks
    double* pF = pT + NB;

    const float c0 = -0.2f / ((float)N0 * (float)N0);
    const float c1 = -0.2f / ((float)N1 * (float)N1);
    const float c2 = -0.2f / ((float)N2 * (float)N2);

    k_res_restrict<<<dim3(N0 / 256, N0 / 16), 256, 0, stream>>>(f0, f1, N0, N1);
    k_res_restrict<<<dim3(N1 / 256, N1 / 16), 256, 0, stream>>>(f1, f2, N1, N2);
    k_smooth_wide<false><<<dim3(N1 / 256, N1 / 16), 512, 0, stream>>>(
        f1, f2, u1, N1, N2, c1, c2, nullptr, nullptr);
    k_smooth_wide<true><<<dim3(N0 / 256, N0 / 16), 512, 0, stream>>>(
        f0, u1, u0, N0, N1, c0, 1.0f, pT, pF);
    k_final<<<1, 256, 0, stream>>>(pT, pF, NB, res);
}